// Round 10
// baseline (42.649 us; speedup 1.0000x reference)
//
#include <hip/hip_runtime.h>

typedef float f4 __attribute__((ext_vector_type(4)));
typedef float f4u __attribute__((ext_vector_type(4), aligned(4)));

struct M3 { float m[3][3]; };

#define ELEM(q, n) ((q)[(n) >> 2][(n) & 3])

__device__ __forceinline__ M3 matmul(const M3& A, const M3& B) {  // A @ B
  M3 C;
#pragma unroll
  for (int i = 0; i < 3; ++i)
#pragma unroll
    for (int j = 0; j < 3; ++j)
      C.m[i][j] = A.m[i][0]*B.m[0][j] + A.m[i][1]*B.m[1][j] + A.m[i][2]*B.m[2][j];
  return C;
}

// matrix k (0..7) of the 8-frame window held in 18 f4 regs; k compile-time
__device__ __forceinline__ M3 mk18(const f4 (&q)[18], int k) {
  M3 A;
#pragma unroll
  for (int i = 0; i < 3; ++i)
#pragma unroll
    for (int j = 0; j < 3; ++j)
      A.m[i][j] = ELEM(q, 9*k + 3*i + j);
  return A;
}

template <int CTRL>
__device__ __forceinline__ float dppf(float v) {
  return __int_as_float(
      __builtin_amdgcn_mov_dpp(__float_as_int(v), CTRL, 0xf, 0xf, true));
}

template <int D>  // row_shr:D (8-lane subgroups are 8-aligned; masked by s>=D)
__device__ __forceinline__ M3 dpp_shr_mat(const M3& A) {
  M3 C;
#pragma unroll
  for (int i = 0; i < 3; ++i)
#pragma unroll
    for (int j = 0; j < 3; ++j)
      C.m[i][j] = dppf<0x110 + D>(A.m[i][j]);
  return C;
}

__device__ __forceinline__ float sigm(float z) {
  return __builtin_amdgcn_rcpf(1.0f + __expf(-z));
}
__device__ __forceinline__ float tanh_(float z) {
  float e = __expf(2.0f * z);
  return 1.0f - 2.0f * __builtin_amdgcn_rcpf(e + 1.0f);
}

template <int CTRL>  // quad_perm broadcast within each 4-lane quad
__device__ __forceinline__ float quad_bcast(float v) {
  return __int_as_float(
      __builtin_amdgcn_mov_dpp(__float_as_int(v), CTRL, 0xf, 0xf, true));
}

// Block = 128 threads (2 waves), 16 elements. Each wave: 8 elements, both
// chains. All 36 dwordx4 loads are pinned live (asm) so they issue up front
// and stay in flight (~36 KB/wave). LSTM runs on ALL 64 lanes of wave 0
// (16 elements x 4 gate-lanes) after a barrier.
__global__ __launch_bounds__(128, 2) void fused_kernel(
    const float* __restrict__ dir, const float* __restrict__ R,
    const float* __restrict__ Wih, const float* __restrict__ Whh,
    const float* __restrict__ bih, const float* __restrict__ bhh,
    float* __restrict__ out, int B) {
  __shared__ __align__(16) f4 xrows[64 * 16];  // [t][e], 16 KB

  const int tid = threadIdx.x;
  const int lane = tid & 63;
  const int e = tid >> 3;        // element 0..15 (8 per wave)
  const int s = tid & 7;         // segment within chain
  const int b0 = blockIdx.x * 16;
  const int b = b0 + e;
  const bool valid = (b < B);
  const int bc = valid ? b : (B - 1);
  const f4* Rb4 = (const f4*)(R + (size_t)bc * 1152);

  // ---- issue ALL loads, then pin them live so the compiler can't re-sink ----
  f4 q[18], qf[18];
  {
    const f4* pb = Rb4 + 18 * (7 - s);    // back: frames 56-8s .. 63-8s
    const f4* pf = Rb4 + 144 + 18 * s;    // fwd:  frames 64+8s .. 71+8s
#pragma unroll
    for (int i = 0; i < 18; ++i) q[i] = pb[i];
#pragma unroll
    for (int i = 0; i < 18; ++i) qf[i] = pf[i];
  }
#pragma unroll
  for (int i = 0; i < 18; ++i) asm volatile("" :: "v"(q[i]));
#pragma unroll
  for (int i = 0; i < 18; ++i) asm volatile("" :: "v"(qf[i]));

  const float d0 = dir[3*bc+0], d1 = dir[3*bc+1], d2 = dir[3*bc+2];

  // ======================= BACK chain =======================
  {
    // P = A_{lo+7} @ ... @ A_{lo}
    M3 P = mk18(q, 0);
#pragma unroll
    for (int k = 1; k < 8; ++k) P = matmul(mk18(q, k), P);

    // K-order scan (prev on LEFT): I_s = P_0 @ P_1 @ ... @ P_s
    M3 I = P;
    {
      M3 Sh = dpp_shr_mat<1>(I); M3 T = matmul(Sh, I);
#pragma unroll
      for (int i = 0; i < 3; ++i)
#pragma unroll
        for (int j = 0; j < 3; ++j) I.m[i][j] = (s >= 1) ? T.m[i][j] : I.m[i][j];
    }
    {
      M3 Sh = dpp_shr_mat<2>(I); M3 T = matmul(Sh, I);
#pragma unroll
      for (int i = 0; i < 3; ++i)
#pragma unroll
        for (int j = 0; j < 3; ++j) I.m[i][j] = (s >= 2) ? T.m[i][j] : I.m[i][j];
    }
    {
      M3 Sh = dpp_shr_mat<4>(I); M3 T = matmul(Sh, I);
#pragma unroll
      for (int i = 0; i < 3; ++i)
#pragma unroll
        for (int j = 0; j < 3; ++j) I.m[i][j] = (s >= 4) ? T.m[i][j] : I.m[i][j];
    }

    // w = I^T @ d
    float w0 = I.m[0][0]*d0 + I.m[1][0]*d1 + I.m[2][0]*d2;
    float w1 = I.m[0][1]*d0 + I.m[1][1]*d1 + I.m[2][1]*d2;
    float w2 = I.m[0][2]*d0 + I.m[1][2]*d1 + I.m[2][2]*d2;
    float p0 = dppf<0x111>(w0), p1 = dppf<0x111>(w1), p2 = dppf<0x111>(w2);
    float v0 = (s == 0) ? d0 : p0;
    float v1 = (s == 0) ? d1 : p1;
    float v2 = (s == 0) ? d2 : p2;

    // rows r_j = A_{lo+7-j}^T @ r_{j-1} (row-vector form)
    float row[24];
#pragma unroll
    for (int j = 0; j < 8; ++j) {
      M3 A = mk18(q, 7 - j);
      float n0 = v0*A.m[0][0] + v1*A.m[1][0] + v2*A.m[2][0];
      float n1 = v0*A.m[0][1] + v1*A.m[1][1] + v2*A.m[2][1];
      float n2 = v0*A.m[0][2] + v1*A.m[1][2] + v2*A.m[2][2];
      v0 = n0; v1 = n1; v2 = n2;
      row[3*j+0] = n0; row[3*j+1] = n1; row[3*j+2] = n2;
    }

    if (valid) {  // rows 8s..8s+7: 24 floats, 16B-aligned
      float* ob = out + (size_t)b * 384 + 24 * s;
#pragma unroll
      for (int kk = 0; kk < 6; ++kk) {
        f4 vv = { row[4*kk+0], row[4*kk+1], row[4*kk+2], row[4*kk+3] };
        ((f4*)ob)[kk] = vv;
      }
    }
#pragma unroll
    for (int j = 0; j < 8; ++j) {
      f4 vv = { row[3*j+0], row[3*j+1], row[3*j+2], 0.f };
      xrows[(8*s + j) * 16 + e] = vv;
    }
  }

  // ======================= FWD chain =======================
  {
    M3 P = mk18(qf, 0);
#pragma unroll
    for (int k = 1; k < 8; ++k) P = matmul(mk18(qf, k), P);

    // fwd scan: I_s = S_s @ S_{s-1} @ ... @ S_0
    M3 I = P;
    {
      M3 Sh = dpp_shr_mat<1>(I); M3 T = matmul(I, Sh);
#pragma unroll
      for (int i = 0; i < 3; ++i)
#pragma unroll
        for (int j = 0; j < 3; ++j) I.m[i][j] = (s >= 1) ? T.m[i][j] : I.m[i][j];
    }
    {
      M3 Sh = dpp_shr_mat<2>(I); M3 T = matmul(I, Sh);
#pragma unroll
      for (int i = 0; i < 3; ++i)
#pragma unroll
        for (int j = 0; j < 3; ++j) I.m[i][j] = (s >= 2) ? T.m[i][j] : I.m[i][j];
    }
    {
      M3 Sh = dpp_shr_mat<4>(I); M3 T = matmul(I, Sh);
#pragma unroll
      for (int i = 0; i < 3; ++i)
#pragma unroll
        for (int j = 0; j < 3; ++j) I.m[i][j] = (s >= 4) ? T.m[i][j] : I.m[i][j];
    }

    float w0 = I.m[0][0]*d0 + I.m[0][1]*d1 + I.m[0][2]*d2;
    float w1 = I.m[1][0]*d0 + I.m[1][1]*d1 + I.m[1][2]*d2;
    float w2 = I.m[2][0]*d0 + I.m[2][1]*d1 + I.m[2][2]*d2;
    float p0 = dppf<0x111>(w0), p1 = dppf<0x111>(w1), p2 = dppf<0x111>(w2);
    float v0 = (s == 0) ? d0 : p0;
    float v1 = (s == 0) ? d1 : p1;
    float v2 = (s == 0) ? d2 : p2;

    float row[24];
#pragma unroll
    for (int j = 0; j < 8; ++j) {
      M3 A = mk18(qf, j);
      float n0 = A.m[0][0]*v0 + A.m[0][1]*v1 + A.m[0][2]*v2;
      float n1 = A.m[1][0]*v0 + A.m[1][1]*v1 + A.m[1][2]*v2;
      float n2 = A.m[2][0]*v0 + A.m[2][1]*v1 + A.m[2][2]*v2;
      v0 = n0; v1 = n1; v2 = n2;
      row[3*j+0] = n0; row[3*j+1] = n1; row[3*j+2] = n2;
    }

    if (valid) {  // rows 65+8s .. (s=7: only 7 rows)
      float* ob = out + (size_t)b * 384 + (size_t)(65 + 8*s) * 3;
#pragma unroll
      for (int kk = 0; kk < 5; ++kk) {
        f4u vv = { row[4*kk+0], row[4*kk+1], row[4*kk+2], row[4*kk+3] };
        *(f4u*)(ob + 4*kk) = vv;
      }
      ob[20] = row[20];
      if (s < 7) { ob[21] = row[21]; ob[22] = row[22]; ob[23] = row[23]; }
    }
  }

  __syncthreads();
  if (tid >= 64) return;

  // ============ LSTM: full wave 0, 16 elements x 4 lanes ============
  const int e2 = lane >> 2;            // element 0..15
  const int u = lane & 3, uu = (u == 3) ? 0 : u;
  const int b2 = b0 + e2;
  const bool valid2 = (b2 < B);
  const int b2c = valid2 ? b2 : 0;

  const float wii0 = Wih[uu*3+0],     wii1 = Wih[uu*3+1],     wii2 = Wih[uu*3+2];
  const float wif0 = Wih[(3+uu)*3+0], wif1 = Wih[(3+uu)*3+1], wif2 = Wih[(3+uu)*3+2];
  const float wig0 = Wih[(6+uu)*3+0], wig1 = Wih[(6+uu)*3+1], wig2 = Wih[(6+uu)*3+2];
  const float wio0 = Wih[(9+uu)*3+0], wio1 = Wih[(9+uu)*3+1], wio2 = Wih[(9+uu)*3+2];
  const float whi0 = Whh[uu*3+0],     whi1 = Whh[uu*3+1],     whi2 = Whh[uu*3+2];
  const float whf0 = Whh[(3+uu)*3+0], whf1 = Whh[(3+uu)*3+1], whf2 = Whh[(3+uu)*3+2];
  const float whg0 = Whh[(6+uu)*3+0], whg1 = Whh[(6+uu)*3+1], whg2 = Whh[(6+uu)*3+2];
  const float who0 = Whh[(9+uu)*3+0], who1 = Whh[(9+uu)*3+1], who2 = Whh[(9+uu)*3+2];
  const float bsi = bih[uu]   + bhh[uu];
  const float bsf = bih[3+uu] + bhh[3+uu];
  const float bsg = bih[6+uu] + bhh[6+uu];
  const float bso = bih[9+uu] + bhh[9+uu];
  const float dd0 = dir[3*b2c+0], dd1 = dir[3*b2c+1], dd2 = dir[3*b2c+2];

  float h0 = 0.f, h1 = 0.f, h2 = 0.f, cc = 0.f, hl = 0.f;

#define LSTEP(x0_, x1_, x2_)                                                  \
  {                                                                           \
    float zi = bsi + wii0*(x0_) + wii1*(x1_) + wii2*(x2_)                     \
                   + whi0*h0 + whi1*h1 + whi2*h2;                             \
    float zf = bsf + wif0*(x0_) + wif1*(x1_) + wif2*(x2_)                     \
                   + whf0*h0 + whf1*h1 + whf2*h2;                             \
    float zg = bsg + wig0*(x0_) + wig1*(x1_) + wig2*(x2_)                     \
                   + whg0*h0 + whg1*h1 + whg2*h2;                             \
    float zo = bso + wio0*(x0_) + wio1*(x1_) + wio2*(x2_)                     \
                   + who0*h0 + who1*h1 + who2*h2;                             \
    float ai = sigm(zi), af = sigm(zf), ag = tanh_(zg), ao = sigm(zo);        \
    cc = af*cc + ai*ag;                                                       \
    float hn = ao * tanh_(cc);                                                \
    hl = hn;                                                                  \
    h0 = quad_bcast<0x00>(hn);                                                \
    h1 = quad_bcast<0x55>(hn);                                                \
    h2 = quad_bcast<0xAA>(hn);                                                \
  }

#pragma unroll 1
  for (int c = 0; c < 8; ++c) {
    f4 xa[8];
#pragma unroll
    for (int j = 0; j < 8; ++j) xa[j] = xrows[(c * 8 + j) * 16 + e2];
#pragma unroll
    for (int j = 0; j < 8; ++j) LSTEP(xa[j][0], xa[j][1], xa[j][2]);
  }
  LSTEP(dd0, dd1, dd2);  // final step t=64 with x = dir
#undef LSTEP

  if (valid2 && u < 3) out[(size_t)b2 * 384 + 192 + u] = hl;
}

extern "C" void kernel_launch(void* const* d_in, const int* in_sizes, int n_in,
                              void* d_out, int out_size, void* d_ws, size_t ws_size,
                              hipStream_t stream) {
  const float* dir = (const float*)d_in[0];
  const float* R   = (const float*)d_in[1];
  const float* Wih = (const float*)d_in[2];
  const float* Whh = (const float*)d_in[3];
  const float* bih = (const float*)d_in[4];
  const float* bhh = (const float*)d_in[5];
  float* out = (float*)d_out;

  const int B = in_sizes[0] / 3;   // 16384
  const int grid = (B + 15) / 16;  // 1024 blocks of 128 threads
  hipLaunchKernelGGL(fused_kernel, dim3(grid), dim3(128), 0, stream,
                     dir, R, Wih, Whh, bih, bhh, out, B);
}

// Round 11
// 34.385 us; speedup vs baseline: 1.2404x; 1.2404x over previous
//
#include <hip/hip_runtime.h>

typedef float f4 __attribute__((ext_vector_type(4)));
typedef float f4u __attribute__((ext_vector_type(4), aligned(4)));

struct M3 { float m[3][3]; };

#define ELEM(q, n) ((q)[(n) >> 2][(n) & 3])

__device__ __forceinline__ M3 matmul(const M3& A, const M3& B) {  // A @ B
  M3 C;
#pragma unroll
  for (int i = 0; i < 3; ++i)
#pragma unroll
    for (int j = 0; j < 3; ++j)
      C.m[i][j] = A.m[i][0]*B.m[0][j] + A.m[i][1]*B.m[1][j] + A.m[i][2]*B.m[2][j];
  return C;
}

// matrix k (0..7) of the 8-frame window held in 18 f4 regs; k compile-time
__device__ __forceinline__ M3 mk18(const f4 (&q)[18], int k) {
  M3 A;
#pragma unroll
  for (int i = 0; i < 3; ++i)
#pragma unroll
    for (int j = 0; j < 3; ++j)
      A.m[i][j] = ELEM(q, 9*k + 3*i + j);
  return A;
}

template <int CTRL>
__device__ __forceinline__ float dppf(float v) {
  return __int_as_float(
      __builtin_amdgcn_mov_dpp(__float_as_int(v), CTRL, 0xf, 0xf, true));
}

template <int D>  // row_shr:D (8-lane subgroups are 8-aligned; masked by s>=D)
__device__ __forceinline__ M3 dpp_shr_mat(const M3& A) {
  M3 C;
#pragma unroll
  for (int i = 0; i < 3; ++i)
#pragma unroll
    for (int j = 0; j < 3; ++j)
      C.m[i][j] = dppf<0x110 + D>(A.m[i][j]);
  return C;
}

__device__ __forceinline__ float sigm(float z) {
  return __builtin_amdgcn_rcpf(1.0f + __expf(-z));
}
__device__ __forceinline__ float tanh_(float z) {
  float e = __expf(2.0f * z);
  return 1.0f - 2.0f * __builtin_amdgcn_rcpf(e + 1.0f);
}

template <int CTRL>  // quad_perm broadcast within each 4-lane quad
__device__ __forceinline__ float quad_bcast(float v) {
  return __int_as_float(
      __builtin_amdgcn_mov_dpp(__float_as_int(v), CTRL, 0xf, 0xf, true));
}

// Persistent 1-wave blocks: each block owns 16 elements and LOOPS over
// 4 chain iterations (2 groups x {back,fwd}) with a shared small body
// (I-cache resident after lap 1), then loops the LSTM. Next iteration's
// 18 loads are issued before compute (VGPR double buffer) for MLP.
__global__ __launch_bounds__(64) void fused_kernel(
    const float* __restrict__ dir, const float* __restrict__ R,
    const float* __restrict__ Wih, const float* __restrict__ Whh,
    const float* __restrict__ bih, const float* __restrict__ bhh,
    float* __restrict__ out, int B) {
  __shared__ __align__(16) f4 xrows[64 * 16];  // [t][elem 0..15], 16 KB

  const int lane = threadIdx.x;
  const int e8 = lane >> 3;   // element within group (0..7)
  const int s = lane & 7;     // segment within chain
  const int b0 = blockIdx.x * 16;

  // ---- prologue: load iteration 0 (group 0, back phase) ----
  f4 qN[18];
  {
    int bn = b0 + e8; bn = (bn < B) ? bn : (B - 1);
    const f4* p = (const f4*)(R + (size_t)bn * 1152) + 18 * (7 - s);
#pragma unroll
    for (int i = 0; i < 18; ++i) qN[i] = p[i];
  }

#pragma unroll 1
  for (int it = 0; it < 4; ++it) {
    const int g = it >> 1;
    const int phase = it & 1;           // 0 = back, 1 = fwd (wave-uniform)
    const int b = b0 + g * 8 + e8;
    const bool valid = (b < B);
    const int bc = valid ? b : (B - 1);

    f4 q[18];
#pragma unroll
    for (int i = 0; i < 18; ++i) q[i] = qN[i];

    if (it < 3) {  // prefetch next iteration
      const int itn = it + 1;
      int bn = b0 + (itn >> 1) * 8 + e8; bn = (bn < B) ? bn : (B - 1);
      const f4* p = (const f4*)(R + (size_t)bn * 1152) +
                    ((itn & 1) ? (144 + 18 * s) : (18 * (7 - s)));
#pragma unroll
      for (int i = 0; i < 18; ++i) qN[i] = p[i];
    }

    const float d0 = dir[3*bc+0], d1 = dir[3*bc+1], d2 = dir[3*bc+2];

    // ---- segment product P = A7 @ ... @ A0 (shared both phases) ----
    M3 P = mk18(q, 0);
#pragma unroll
    for (int k = 1; k < 8; ++k) P = matmul(mk18(q, k), P);

    // ---- 8-lane DPP scan; combine order depends on phase (uniform) ----
    M3 I = P;
    {
      M3 Sh = dpp_shr_mat<1>(I);
      M3 T; if (phase == 0) T = matmul(Sh, I); else T = matmul(I, Sh);
#pragma unroll
      for (int i = 0; i < 3; ++i)
#pragma unroll
        for (int j = 0; j < 3; ++j) I.m[i][j] = (s >= 1) ? T.m[i][j] : I.m[i][j];
    }
    {
      M3 Sh = dpp_shr_mat<2>(I);
      M3 T; if (phase == 0) T = matmul(Sh, I); else T = matmul(I, Sh);
#pragma unroll
      for (int i = 0; i < 3; ++i)
#pragma unroll
        for (int j = 0; j < 3; ++j) I.m[i][j] = (s >= 2) ? T.m[i][j] : I.m[i][j];
    }
    {
      M3 Sh = dpp_shr_mat<4>(I);
      M3 T; if (phase == 0) T = matmul(Sh, I); else T = matmul(I, Sh);
#pragma unroll
      for (int i = 0; i < 3; ++i)
#pragma unroll
        for (int j = 0; j < 3; ++j) I.m[i][j] = (s >= 4) ? T.m[i][j] : I.m[i][j];
    }

    if (phase == 0) {
      // ======== BACK: w = I^T d; rows r <- r^T A; rows 8s..8s+7 ========
      float w0 = I.m[0][0]*d0 + I.m[1][0]*d1 + I.m[2][0]*d2;
      float w1 = I.m[0][1]*d0 + I.m[1][1]*d1 + I.m[2][1]*d2;
      float w2 = I.m[0][2]*d0 + I.m[1][2]*d1 + I.m[2][2]*d2;
      float p0 = dppf<0x111>(w0), p1 = dppf<0x111>(w1), p2 = dppf<0x111>(w2);
      float v0 = (s == 0) ? d0 : p0;
      float v1 = (s == 0) ? d1 : p1;
      float v2 = (s == 0) ? d2 : p2;

      float row[24];
#pragma unroll
      for (int j = 0; j < 8; ++j) {
        M3 A = mk18(q, 7 - j);
        float n0 = v0*A.m[0][0] + v1*A.m[1][0] + v2*A.m[2][0];
        float n1 = v0*A.m[0][1] + v1*A.m[1][1] + v2*A.m[2][1];
        float n2 = v0*A.m[0][2] + v1*A.m[1][2] + v2*A.m[2][2];
        v0 = n0; v1 = n1; v2 = n2;
        row[3*j+0] = n0; row[3*j+1] = n1; row[3*j+2] = n2;
      }

      if (valid) {
        float* ob = out + (size_t)b * 384 + 24 * s;
#pragma unroll
        for (int kk = 0; kk < 6; ++kk) {
          f4 vv = { row[4*kk+0], row[4*kk+1], row[4*kk+2], row[4*kk+3] };
          ((f4*)ob)[kk] = vv;
        }
      }
#pragma unroll
      for (int j = 0; j < 8; ++j) {
        f4 vv = { row[3*j+0], row[3*j+1], row[3*j+2], 0.f };
        xrows[(8*s + j) * 16 + g * 8 + e8] = vv;
      }
    } else {
      // ======== FWD: w = I d; rows r <- A r; rows 65+8s.. ========
      float w0 = I.m[0][0]*d0 + I.m[0][1]*d1 + I.m[0][2]*d2;
      float w1 = I.m[1][0]*d0 + I.m[1][1]*d1 + I.m[1][2]*d2;
      float w2 = I.m[2][0]*d0 + I.m[2][1]*d1 + I.m[2][2]*d2;
      float p0 = dppf<0x111>(w0), p1 = dppf<0x111>(w1), p2 = dppf<0x111>(w2);
      float v0 = (s == 0) ? d0 : p0;
      float v1 = (s == 0) ? d1 : p1;
      float v2 = (s == 0) ? d2 : p2;

      float row[24];
#pragma unroll
      for (int j = 0; j < 8; ++j) {
        M3 A = mk18(q, j);
        float n0 = A.m[0][0]*v0 + A.m[0][1]*v1 + A.m[0][2]*v2;
        float n1 = A.m[1][0]*v0 + A.m[1][1]*v1 + A.m[1][2]*v2;
        float n2 = A.m[2][0]*v0 + A.m[2][1]*v1 + A.m[2][2]*v2;
        v0 = n0; v1 = n1; v2 = n2;
        row[3*j+0] = n0; row[3*j+1] = n1; row[3*j+2] = n2;
      }

      if (valid) {
        float* ob = out + (size_t)b * 384 + (size_t)(65 + 8*s) * 3;
#pragma unroll
        for (int kk = 0; kk < 5; ++kk) {
          f4u vv = { row[4*kk+0], row[4*kk+1], row[4*kk+2], row[4*kk+3] };
          *(f4u*)(ob + 4*kk) = vv;
        }
        ob[20] = row[20];
        if (s < 7) { ob[21] = row[21]; ob[22] = row[22]; ob[23] = row[23]; }
      }
    }
  }

  // ============ LSTM: 16 elements x 4 lanes = full wave ============
  // single-wave block: LDS writes above are ordered before these reads
  const int e2 = lane >> 2;            // element 0..15
  const int u = lane & 3, uu = (u == 3) ? 0 : u;
  const int b2 = b0 + e2;
  const bool valid2 = (b2 < B);
  const int b2c = valid2 ? b2 : 0;

  const float wii0 = Wih[uu*3+0],     wii1 = Wih[uu*3+1],     wii2 = Wih[uu*3+2];
  const float wif0 = Wih[(3+uu)*3+0], wif1 = Wih[(3+uu)*3+1], wif2 = Wih[(3+uu)*3+2];
  const float wig0 = Wih[(6+uu)*3+0], wig1 = Wih[(6+uu)*3+1], wig2 = Wih[(6+uu)*3+2];
  const float wio0 = Wih[(9+uu)*3+0], wio1 = Wih[(9+uu)*3+1], wio2 = Wih[(9+uu)*3+2];
  const float whi0 = Whh[uu*3+0],     whi1 = Whh[uu*3+1],     whi2 = Whh[uu*3+2];
  const float whf0 = Whh[(3+uu)*3+0], whf1 = Whh[(3+uu)*3+1], whf2 = Whh[(3+uu)*3+2];
  const float whg0 = Whh[(6+uu)*3+0], whg1 = Whh[(6+uu)*3+1], whg2 = Whh[(6+uu)*3+2];
  const float who0 = Whh[(9+uu)*3+0], who1 = Whh[(9+uu)*3+1], who2 = Whh[(9+uu)*3+2];
  const float bsi = bih[uu]   + bhh[uu];
  const float bsf = bih[3+uu] + bhh[3+uu];
  const float bsg = bih[6+uu] + bhh[6+uu];
  const float bso = bih[9+uu] + bhh[9+uu];
  const float dd0 = dir[3*b2c+0], dd1 = dir[3*b2c+1], dd2 = dir[3*b2c+2];

  float h0 = 0.f, h1 = 0.f, h2 = 0.f, cc = 0.f, hl = 0.f;

#define LSTEP(x0_, x1_, x2_)                                                  \
  {                                                                           \
    float zi = bsi + wii0*(x0_) + wii1*(x1_) + wii2*(x2_)                     \
                   + whi0*h0 + whi1*h1 + whi2*h2;                             \
    float zf = bsf + wif0*(x0_) + wif1*(x1_) + wif2*(x2_)                     \
                   + whf0*h0 + whf1*h1 + whf2*h2;                             \
    float zg = bsg + wig0*(x0_) + wig1*(x1_) + wig2*(x2_)                     \
                   + whg0*h0 + whg1*h1 + whg2*h2;                             \
    float zo = bso + wio0*(x0_) + wio1*(x1_) + wio2*(x2_)                     \
                   + who0*h0 + who1*h1 + who2*h2;                             \
    float ai = sigm(zi), af = sigm(zf), ag = tanh_(zg), ao = sigm(zo);        \
    cc = af*cc + ai*ag;                                                       \
    float hn = ao * tanh_(cc);                                                \
    hl = hn;                                                                  \
    h0 = quad_bcast<0x00>(hn);                                                \
    h1 = quad_bcast<0x55>(hn);                                                \
    h2 = quad_bcast<0xAA>(hn);                                                \
  }

#pragma unroll 1
  for (int c = 0; c < 8; ++c) {
    f4 xa[8];
#pragma unroll
    for (int j = 0; j < 8; ++j) xa[j] = xrows[(c * 8 + j) * 16 + e2];
#pragma unroll
    for (int j = 0; j < 8; ++j) LSTEP(xa[j][0], xa[j][1], xa[j][2]);
  }
  LSTEP(dd0, dd1, dd2);  // final step t=64 with x = dir
#undef LSTEP

  if (valid2 && u < 3) out[(size_t)b2 * 384 + 192 + u] = hl;
}

extern "C" void kernel_launch(void* const* d_in, const int* in_sizes, int n_in,
                              void* d_out, int out_size, void* d_ws, size_t ws_size,
                              hipStream_t stream) {
  const float* dir = (const float*)d_in[0];
  const float* R   = (const float*)d_in[1];
  const float* Wih = (const float*)d_in[2];
  const float* Whh = (const float*)d_in[3];
  const float* bih = (const float*)d_in[4];
  const float* bhh = (const float*)d_in[5];
  float* out = (float*)d_out;

  const int B = in_sizes[0] / 3;   // 16384
  const int grid = (B + 15) / 16;  // 1024 one-wave blocks, 4/CU
  hipLaunchKernelGGL(fused_kernel, dim3(grid), dim3(64), 0, stream,
                     dir, R, Wih, Whh, bih, bhh, out, B);
}